// Round 10
// baseline (324.913 us; speedup 1.0000x reference)
//
#include <hip/hip_runtime.h>
#include <hip/hip_fp16.h>

#define N_NODES 100000
#define N_EDGES 1600000
#define D 64

#define NB 2048                 // buckets (power of 2)
#define BUCKET_W 49             // nodes per bucket
#define NB_USED ((N_NODES + BUCKET_W - 1) / BUCKET_W)   // 2041
#define NBLK 32                 // partition blocks (exact per-block regions)
#define CHUNK32 ((N_EDGES + NBLK - 1) / NBLK)           // 50000
#define CCAP 1536               // max edges per bucket (mean 784, sd ~28)

// ---------------- pass A: per-block LDS histogram -> gcount[b*NBLK+blk] ----------------
__global__ __launch_bounds__(256) void bucket_count(const int* __restrict__ dst,
                                                    int* __restrict__ gcount) {
    __shared__ int h[NB];
    for (int i = threadIdx.x; i < NB; i += 256) h[i] = 0;
    __syncthreads();
    const int blk = blockIdx.x;
    const int beg = blk * CHUNK32;
    const int end = min(beg + CHUNK32, N_EDGES);
    for (int e = beg + threadIdx.x; e < end; e += 256)
        atomicAdd(&h[dst[e] / BUCKET_W], 1);
    __syncthreads();
    for (int i = threadIdx.x; i < NB; i += 256)
        gcount[i * NBLK + blk] = h[i];     // exact count, no global atomics
}

// ---------------- exact scan of 65536 (bucket,block) counts -> subbase ----------------
__global__ __launch_bounds__(1024) void scan64k(const int* __restrict__ gcount,
                                                int* __restrict__ subbase) {
    __shared__ int s[1024];
    const int t = threadIdx.x;
    int loc[64];
    int sum = 0;
#pragma unroll
    for (int i = 0; i < 64; ++i) { loc[i] = gcount[t * 64 + i]; sum += loc[i]; }
    s[t] = sum;
    __syncthreads();
    for (int off = 1; off < 1024; off <<= 1) {
        int u = (t >= off) ? s[t - off] : 0;
        __syncthreads();
        s[t] += u;
        __syncthreads();
    }
    int excl = s[t] - sum;
#pragma unroll
    for (int i = 0; i < 64; ++i) { subbase[t * 64 + i] = excl; excl += loc[i]; }
    if (t == 1023) subbase[NB * NBLK] = excl;   // == N_EDGES
}

// ---------------- pass B: partition with LDS cursors (no global atomics) ----------------
__global__ __launch_bounds__(256) void partition_edges(const int* __restrict__ src,
                                                       const int* __restrict__ dst,
                                                       const int* __restrict__ subbase,
                                                       int* __restrict__ part) {
    __shared__ int cur[NB];
    const int blk = blockIdx.x;
    for (int i = threadIdx.x; i < NB; i += 256) cur[i] = subbase[i * NBLK + blk];
    __syncthreads();
    const int beg = blk * CHUNK32;
    const int end = min(beg + CHUNK32, N_EDGES);
    for (int e = beg + threadIdx.x; e < end; e += 256) {
        const int d = dst[e];
        const int s = src[e];
        const int b = d / BUCKET_W;
        const int pos = atomicAdd(&cur[b], 1);         // LDS atomic
        part[pos] = (s << 6) | (d - b * BUCKET_W);     // ~24 edges per region: lines fill in L2
    }
}

// ---------------- pass C: per-bucket counting sort -> col, rowptr, dinv ----------------
__global__ __launch_bounds__(256) void bucket_csr(const int* __restrict__ subbase,
                                                  const int* __restrict__ part,
                                                  int* __restrict__ col,
                                                  int* __restrict__ rowptr,
                                                  float* __restrict__ dinv) {
    __shared__ int ed[CCAP];
    __shared__ int hist[BUCKET_W];
    __shared__ int offs[BUCKET_W];
    __shared__ int lcur[BUCKET_W];
    const int b = blockIdx.x;
    const int base = subbase[b * NBLK];
    const int cnt = min(subbase[(b + 1) * NBLK] - base, CCAP);
    const int n0 = b * BUCKET_W;
    const int nn = min(N_NODES - n0, BUCKET_W);
    const int t = threadIdx.x;

    if (t < BUCKET_W) hist[t] = 0;
    for (int i = t; i < cnt; i += 256) ed[i] = part[base + i];
    __syncthreads();
    for (int i = t; i < cnt; i += 256) atomicAdd(&hist[ed[i] & 63], 1);
    __syncthreads();
    if (t == 0) {
        int a = 0;
        for (int i = 0; i < nn; ++i) { offs[i] = a; lcur[i] = a; a += hist[i]; }
    }
    __syncthreads();
    if (t < nn) {
        rowptr[n0 + t] = base + offs[t];
        dinv[n0 + t] = rsqrtf((float)hist[t] + 1.0f);
        if (b == NB_USED - 1 && t == 0) rowptr[N_NODES] = N_EDGES;
    }
    __syncthreads();
    for (int i = t; i < cnt; i += 256) {
        const int p = ed[i];
        const int pos = atomicAdd(&lcur[p & 63], 1);
        col[base + pos] = p >> 6;
    }
}

// ---------------- xsc[n] = (half)(x[n] * dinv[n])  [row-major fp16] ----------------
__global__ void convert_scale(const float* __restrict__ x, const float* __restrict__ dinv,
                              __half* __restrict__ xh) {
    int t = blockIdx.x * blockDim.x + threadIdx.x;
    if (t >= N_NODES * 8) return;
    const int node = t >> 3, oct = t & 7;
    const float dv = dinv[node];
    const float2* xr = (const float2*)(x + (size_t)node * 64 + oct * 8);
    __half2* xw = (__half2*)(xh + (size_t)node * 64 + oct * 8);
#pragma unroll
    for (int i = 0; i < 4; ++i) {
        const float2 v = xr[i];
        xw[i] = __floats2half2_rn(v.x * dv, v.y * dv);
    }
}

// ---------------- aggregation: agg[d] = dv*(sum_{s in N(d)} xsc[s] + xsc[d]) ----------------
__device__ __forceinline__ int rlane_i(int v, int l) {
    return __builtin_amdgcn_readlane(v, l);
}

__global__ __launch_bounds__(256) void agg_rows(const __half* __restrict__ xh,
                                                const int* __restrict__ rowptr,
                                                const int* __restrict__ col,
                                                const float* __restrict__ dinv,
                                                float* __restrict__ agg, int n) {
    const int nd = blockIdx.x * 4 + (threadIdx.x >> 6);
    if (nd >= n) return;
    const int lane = threadIdx.x & 63;
    const int beg = rowptr[nd];
    const int end = rowptr[nd + 1];
    const float dv = dinv[nd];
    const float self = __half2float(xh[(size_t)nd * D + lane]);

    float a0 = 0.f, a1 = 0.f, a2 = 0.f, a3 = 0.f;
    for (int j = beg; j < end; j += 64) {
        const int chunk = min(end - j, 64);
        const int c = (lane < chunk) ? col[j + lane] : 0;   // coalesced 4B/lane
        int t = 0;
        for (; t + 7 < chunk; t += 8) {
            const int s0 = rlane_i(c, t + 0), s1 = rlane_i(c, t + 1);
            const int s2 = rlane_i(c, t + 2), s3 = rlane_i(c, t + 3);
            const int s4 = rlane_i(c, t + 4), s5 = rlane_i(c, t + 5);
            const int s6 = rlane_i(c, t + 6), s7 = rlane_i(c, t + 7);
            a0 += __half2float(xh[(size_t)s0 * D + lane]);
            a1 += __half2float(xh[(size_t)s1 * D + lane]);
            a2 += __half2float(xh[(size_t)s2 * D + lane]);
            a3 += __half2float(xh[(size_t)s3 * D + lane]);
            a0 += __half2float(xh[(size_t)s4 * D + lane]);
            a1 += __half2float(xh[(size_t)s5 * D + lane]);
            a2 += __half2float(xh[(size_t)s6 * D + lane]);
            a3 += __half2float(xh[(size_t)s7 * D + lane]);
        }
        for (; t < chunk; ++t) {
            const int s0 = rlane_i(c, t);
            a0 += __half2float(xh[(size_t)s0 * D + lane]);
        }
    }
    const float sum = (a0 + a1) + (a2 + a3) + self;   // self enters UNSCALED
    agg[(size_t)nd * D + lane] = dv * sum;
}

// ---------------- GEMM: r = relu(agg @ W + b); write fp32 or scaled-fp16 ----------------
__device__ __forceinline__ float rlane_ff(float v, int l) {
    return __int_as_float(__builtin_amdgcn_readlane(__float_as_int(v), l));
}

template <bool SCALED_HALF_OUT>
__global__ __launch_bounds__(256) void gemm64(const float* __restrict__ aggs,
                                              const float* __restrict__ W,
                                              const float* __restrict__ bias,
                                              const float* __restrict__ dinv,
                                              float* __restrict__ out,
                                              __half* __restrict__ outh, int n) {
    const int lane = threadIdx.x & 63;
    const int gwave = (blockIdx.x * blockDim.x + threadIdx.x) >> 6;
    const int nwaves = (gridDim.x * blockDim.x) >> 6;
    float wcol[64];
#pragma unroll
    for (int k = 0; k < 64; ++k) wcol[k] = W[k * 64 + lane];
    const float bv = bias[lane];

    for (int nd = gwave; nd < n; nd += nwaves) {
        const float a = aggs[(size_t)nd * D + lane];
        float g0 = 0.f, g1 = 0.f, g2 = 0.f, g3 = 0.f;
#pragma unroll
        for (int k = 0; k < 64; k += 4) {
            g0 = fmaf(rlane_ff(a, k + 0), wcol[k + 0], g0);
            g1 = fmaf(rlane_ff(a, k + 1), wcol[k + 1], g1);
            g2 = fmaf(rlane_ff(a, k + 2), wcol[k + 2], g2);
            g3 = fmaf(rlane_ff(a, k + 3), wcol[k + 3], g3);
        }
        const float r = fmaxf((g0 + g1) + (g2 + g3) + bv, 0.f);
        if (SCALED_HALF_OUT)
            outh[(size_t)nd * D + lane] = __float2half(r * dinv[nd]);
        else
            out[(size_t)nd * D + lane] = r;
    }
}

extern "C" void kernel_launch(void* const* d_in, const int* in_sizes, int n_in,
                              void* d_out, int out_size, void* d_ws, size_t ws_size,
                              hipStream_t stream) {
    const float* feature = (const float*)d_in[0];
    const int*   edges   = (const int*)d_in[1];   // [2, E] flat: src then dst
    const float* W1      = (const float*)d_in[2];
    const float* b1      = (const float*)d_in[3];
    const float* W2      = (const float*)d_in[4];
    const float* b2      = (const float*)d_in[5];
    float* out = (float*)d_out;

    const int* src = edges;
    const int* dst = edges + N_EDGES;

    // workspace layout
    char* w = (char*)d_ws;
    int*    gcount  = (int*)w;    w += sizeof(int) * (NB * NBLK);       // 65536
    int*    subbase = (int*)w;    w += sizeof(int) * (NB * NBLK + 1);   // 65537
    int*    rowptr  = (int*)w;    w += sizeof(int) * (N_NODES + 1);
    float*  dinv    = (float*)w;  w += sizeof(float) * (N_NODES);
    int*    part    = (int*)w;    w += sizeof(int) * (N_EDGES);          // 6.4MB
    int*    colA    = (int*)w;    w += sizeof(int) * (N_EDGES);          // 6.4MB
    __half* xh      = (__half*)w; w += sizeof(__half) * ((size_t)N_NODES * D);  // 12.8MB
    __half* y1h     = (__half*)w; w += sizeof(__half) * ((size_t)N_NODES * D);  // 12.8MB
    float*  aggsA   = (float*)w;  w += sizeof(float) * ((size_t)N_NODES * D);   // 25.6MB

    // ---- partition + CSR + scaled-fp16 features (once) ----
    bucket_count<<<NBLK, 256, 0, stream>>>(dst, gcount);
    scan64k<<<1, 1024, 0, stream>>>(gcount, subbase);
    partition_edges<<<NBLK, 256, 0, stream>>>(src, dst, subbase, part);
    bucket_csr<<<NB_USED, 256, 0, stream>>>(subbase, part, colA, rowptr, dinv);
    convert_scale<<<(N_NODES * 8 + 255) / 256, 256, 0, stream>>>(feature, dinv, xh);

    const int agg_blocks = (N_NODES + 3) / 4;

    // ---- layer 1 ----
    agg_rows<<<agg_blocks, 256, 0, stream>>>(xh, rowptr, colA, dinv, aggsA, N_NODES);
    gemm64<true><<<2048, 256, 0, stream>>>(aggsA, W1, b1, dinv, nullptr, y1h, N_NODES);

    // ---- layer 2 ----
    agg_rows<<<agg_blocks, 256, 0, stream>>>(y1h, rowptr, colA, dinv, aggsA, N_NODES);
    gemm64<false><<<2048, 256, 0, stream>>>(aggsA, W2, b2, dinv, out, nullptr, N_NODES);
}

// Round 11
// 228.862 us; speedup vs baseline: 1.4197x; 1.4197x over previous
//
#include <hip/hip_runtime.h>
#include <hip/hip_fp16.h>

#define N_NODES 100000
#define N_EDGES 1600000
#define D 64

#define NB 256                  // fat buckets
#define BUCKET_W 391            // nodes per bucket (256*391 = 100096 >= 100000)
#define NB_USED ((N_NODES + BUCKET_W - 1) / BUCKET_W)   // 256
#define NBLK 256                // partition blocks (exact per-block regions)
#define CHUNK ((N_EDGES + NBLK - 1) / NBLK)             // 6250
#define CCAP 7168               // max edges per bucket (mean 6250, sd ~79)
#define LMASK 511               // 9-bit local node index

// ---------------- pass A: per-block LDS histogram -> gcount[b*NBLK+blk] ----------------
__global__ __launch_bounds__(256) void bucket_count(const int* __restrict__ dst,
                                                    int* __restrict__ gcount) {
    __shared__ int h[NB];
    if (threadIdx.x < NB) h[threadIdx.x] = 0;
    __syncthreads();
    const int blk = blockIdx.x;
    const int beg = blk * CHUNK;
    const int end = min(beg + CHUNK, N_EDGES);
    for (int e = beg + threadIdx.x; e < end; e += 256)
        atomicAdd(&h[dst[e] / BUCKET_W], 1);
    __syncthreads();
    if (threadIdx.x < NB)
        gcount[threadIdx.x * NBLK + blk] = h[threadIdx.x];   // exact, no global atomics
}

// ---------------- exact scan of 65536 (bucket,block) counts -> subbase ----------------
__global__ __launch_bounds__(1024) void scan64k(const int* __restrict__ gcount,
                                                int* __restrict__ subbase) {
    __shared__ int s[1024];
    const int t = threadIdx.x;
    int loc[64];
    int sum = 0;
#pragma unroll
    for (int i = 0; i < 64; ++i) { loc[i] = gcount[t * 64 + i]; sum += loc[i]; }
    s[t] = sum;
    __syncthreads();
    for (int off = 1; off < 1024; off <<= 1) {
        int u = (t >= off) ? s[t - off] : 0;
        __syncthreads();
        s[t] += u;
        __syncthreads();
    }
    int excl = s[t] - sum;
#pragma unroll
    for (int i = 0; i < 64; ++i) { subbase[t * 64 + i] = excl; excl += loc[i]; }
    if (t == 1023) subbase[NB * NBLK] = excl;   // == N_EDGES
}

// ---------------- pass B: partition with LDS cursors (no global atomics) ----------------
__global__ __launch_bounds__(256) void partition_edges(const int* __restrict__ src,
                                                       const int* __restrict__ dst,
                                                       const int* __restrict__ subbase,
                                                       int* __restrict__ part) {
    __shared__ int cur[NB];
    const int blk = blockIdx.x;
    if (threadIdx.x < NB) cur[threadIdx.x] = subbase[threadIdx.x * NBLK + blk];
    __syncthreads();
    const int beg = blk * CHUNK;
    const int end = min(beg + CHUNK, N_EDGES);
    for (int e = beg + threadIdx.x; e < end; e += 256) {
        const int d = dst[e];
        const int s = src[e];
        const int b = d / BUCKET_W;
        const int pos = atomicAdd(&cur[b], 1);          // LDS atomic
        part[pos] = (s << 9) | (d - b * BUCKET_W);      // ~24 edges/region: lines fill
    }
}

// ---------------- pass C: per-bucket counting sort -> col, rowptr, dinv ----------------
__global__ __launch_bounds__(256) void bucket_csr(const int* __restrict__ subbase,
                                                  const int* __restrict__ part,
                                                  int* __restrict__ col,
                                                  int* __restrict__ rowptr,
                                                  float* __restrict__ dinv) {
    __shared__ int ed[CCAP];
    __shared__ int hist[BUCKET_W];
    __shared__ int offs[BUCKET_W];
    __shared__ int lcur[BUCKET_W];
    const int b = blockIdx.x;
    const int base = subbase[b * NBLK];
    const int cnt = min(subbase[(b + 1) * NBLK] - base, CCAP);
    const int n0 = b * BUCKET_W;
    const int nn = min(N_NODES - n0, BUCKET_W);
    const int t = threadIdx.x;

    for (int i = t; i < BUCKET_W; i += 256) hist[i] = 0;
    for (int i = t; i < cnt; i += 256) ed[i] = part[base + i];
    __syncthreads();
    for (int i = t; i < cnt; i += 256) atomicAdd(&hist[ed[i] & LMASK], 1);
    __syncthreads();
    if (t == 0) {
        int a = 0;
        for (int i = 0; i < nn; ++i) { offs[i] = a; lcur[i] = a; a += hist[i]; }
    }
    __syncthreads();
    for (int i = t; i < nn; i += 256) {
        rowptr[n0 + i] = base + offs[i];
        dinv[n0 + i] = rsqrtf((float)hist[i] + 1.0f);
    }
    if (b == NB_USED - 1 && t == 0) rowptr[N_NODES] = N_EDGES;
    __syncthreads();
    for (int i = t; i < cnt; i += 256) {
        const int p = ed[i];
        const int pos = atomicAdd(&lcur[p & LMASK], 1);
        col[base + pos] = p >> 9;
    }
}

// ---------------- xsc[n] = (half)(x[n] * dinv[n])  [row-major fp16] ----------------
__global__ void convert_scale(const float* __restrict__ x, const float* __restrict__ dinv,
                              __half* __restrict__ xh) {
    int t = blockIdx.x * blockDim.x + threadIdx.x;
    if (t >= N_NODES * 8) return;
    const int node = t >> 3, oct = t & 7;
    const float dv = dinv[node];
    const float2* xr = (const float2*)(x + (size_t)node * 64 + oct * 8);
    __half2* xw = (__half2*)(xh + (size_t)node * 64 + oct * 8);
#pragma unroll
    for (int i = 0; i < 4; ++i) {
        const float2 v = xr[i];
        xw[i] = __floats2half2_rn(v.x * dv, v.y * dv);
    }
}

// ---------------- aggregation: agg[d] = dv*(sum_{s in N(d)} xsc[s] + xsc[d]) ----------------
__device__ __forceinline__ int rlane_i(int v, int l) {
    return __builtin_amdgcn_readlane(v, l);
}

__global__ __launch_bounds__(256) void agg_rows(const __half* __restrict__ xh,
                                                const int* __restrict__ rowptr,
                                                const int* __restrict__ col,
                                                const float* __restrict__ dinv,
                                                float* __restrict__ agg, int n) {
    const int nd = blockIdx.x * 4 + (threadIdx.x >> 6);
    if (nd >= n) return;
    const int lane = threadIdx.x & 63;
    const int beg = rowptr[nd];
    const int end = rowptr[nd + 1];
    const float dv = dinv[nd];
    const float self = __half2float(xh[(size_t)nd * D + lane]);

    float a0 = 0.f, a1 = 0.f, a2 = 0.f, a3 = 0.f;
    for (int j = beg; j < end; j += 64) {
        const int chunk = min(end - j, 64);
        const int c = (lane < chunk) ? col[j + lane] : 0;   // coalesced 4B/lane
        int t = 0;
        for (; t + 7 < chunk; t += 8) {
            const int s0 = rlane_i(c, t + 0), s1 = rlane_i(c, t + 1);
            const int s2 = rlane_i(c, t + 2), s3 = rlane_i(c, t + 3);
            const int s4 = rlane_i(c, t + 4), s5 = rlane_i(c, t + 5);
            const int s6 = rlane_i(c, t + 6), s7 = rlane_i(c, t + 7);
            a0 += __half2float(xh[(size_t)s0 * D + lane]);
            a1 += __half2float(xh[(size_t)s1 * D + lane]);
            a2 += __half2float(xh[(size_t)s2 * D + lane]);
            a3 += __half2float(xh[(size_t)s3 * D + lane]);
            a0 += __half2float(xh[(size_t)s4 * D + lane]);
            a1 += __half2float(xh[(size_t)s5 * D + lane]);
            a2 += __half2float(xh[(size_t)s6 * D + lane]);
            a3 += __half2float(xh[(size_t)s7 * D + lane]);
        }
        for (; t < chunk; ++t) {
            const int s0 = rlane_i(c, t);
            a0 += __half2float(xh[(size_t)s0 * D + lane]);
        }
    }
    const float sum = (a0 + a1) + (a2 + a3) + self;   // self enters UNSCALED
    agg[(size_t)nd * D + lane] = dv * sum;
}

// ---------------- GEMM: r = relu(agg @ W + b); write fp32 or scaled-fp16 ----------------
__device__ __forceinline__ float rlane_ff(float v, int l) {
    return __int_as_float(__builtin_amdgcn_readlane(__float_as_int(v), l));
}

template <bool SCALED_HALF_OUT>
__global__ __launch_bounds__(256) void gemm64(const float* __restrict__ aggs,
                                              const float* __restrict__ W,
                                              const float* __restrict__ bias,
                                              const float* __restrict__ dinv,
                                              float* __restrict__ out,
                                              __half* __restrict__ outh, int n) {
    const int lane = threadIdx.x & 63;
    const int gwave = (blockIdx.x * blockDim.x + threadIdx.x) >> 6;
    const int nwaves = (gridDim.x * blockDim.x) >> 6;
    float wcol[64];
#pragma unroll
    for (int k = 0; k < 64; ++k) wcol[k] = W[k * 64 + lane];
    const float bv = bias[lane];

    for (int nd = gwave; nd < n; nd += nwaves) {
        const float a = aggs[(size_t)nd * D + lane];
        float g0 = 0.f, g1 = 0.f, g2 = 0.f, g3 = 0.f;
#pragma unroll
        for (int k = 0; k < 64; k += 4) {
            g0 = fmaf(rlane_ff(a, k + 0), wcol[k + 0], g0);
            g1 = fmaf(rlane_ff(a, k + 1), wcol[k + 1], g1);
            g2 = fmaf(rlane_ff(a, k + 2), wcol[k + 2], g2);
            g3 = fmaf(rlane_ff(a, k + 3), wcol[k + 3], g3);
        }
        const float r = fmaxf((g0 + g1) + (g2 + g3) + bv, 0.f);
        if (SCALED_HALF_OUT)
            outh[(size_t)nd * D + lane] = __float2half(r * dinv[nd]);
        else
            out[(size_t)nd * D + lane] = r;
    }
}

extern "C" void kernel_launch(void* const* d_in, const int* in_sizes, int n_in,
                              void* d_out, int out_size, void* d_ws, size_t ws_size,
                              hipStream_t stream) {
    const float* feature = (const float*)d_in[0];
    const int*   edges   = (const int*)d_in[1];   // [2, E] flat: src then dst
    const float* W1      = (const float*)d_in[2];
    const float* b1      = (const float*)d_in[3];
    const float* W2      = (const float*)d_in[4];
    const float* b2      = (const float*)d_in[5];
    float* out = (float*)d_out;

    const int* src = edges;
    const int* dst = edges + N_EDGES;

    // workspace layout
    char* w = (char*)d_ws;
    int*    gcount  = (int*)w;    w += sizeof(int) * (NB * NBLK);       // 65536
    int*    subbase = (int*)w;    w += sizeof(int) * (NB * NBLK + 1);   // 65537
    int*    rowptr  = (int*)w;    w += sizeof(int) * (N_NODES + 1);
    float*  dinv    = (float*)w;  w += sizeof(float) * (N_NODES);
    int*    part    = (int*)w;    w += sizeof(int) * (N_EDGES);          // 6.4MB
    int*    colA    = (int*)w;    w += sizeof(int) * (N_EDGES);          // 6.4MB
    __half* xh      = (__half*)w; w += sizeof(__half) * ((size_t)N_NODES * D);  // 12.8MB
    __half* y1h     = (__half*)w; w += sizeof(__half) * ((size_t)N_NODES * D);  // 12.8MB
    float*  aggsA   = (float*)w;  w += sizeof(float) * ((size_t)N_NODES * D);   // 25.6MB

    // ---- partition + CSR + scaled-fp16 features (once) ----
    bucket_count<<<NBLK, 256, 0, stream>>>(dst, gcount);
    scan64k<<<1, 1024, 0, stream>>>(gcount, subbase);
    partition_edges<<<NBLK, 256, 0, stream>>>(src, dst, subbase, part);
    bucket_csr<<<NB_USED, 256, 0, stream>>>(subbase, part, colA, rowptr, dinv);
    convert_scale<<<(N_NODES * 8 + 255) / 256, 256, 0, stream>>>(feature, dinv, xh);

    const int agg_blocks = (N_NODES + 3) / 4;

    // ---- layer 1 ----
    agg_rows<<<agg_blocks, 256, 0, stream>>>(xh, rowptr, colA, dinv, aggsA, N_NODES);
    gemm64<true><<<2048, 256, 0, stream>>>(aggsA, W1, b1, dinv, nullptr, y1h, N_NODES);

    // ---- layer 2 ----
    agg_rows<<<agg_blocks, 256, 0, stream>>>(y1h, rowptr, colA, dinv, aggsA, N_NODES);
    gemm64<false><<<2048, 256, 0, stream>>>(aggsA, W2, b2, dinv, out, nullptr, N_NODES);
}